// Round 8
// baseline (1274.021 us; speedup 1.0000x reference)
//
#include <hip/hip_runtime.h>

#define LRC 0.01f
#define LSEQ 4096
#define HIDDIM 128

typedef unsigned int u32x2 __attribute__((ext_vector_type(2)));

// x += row_ror(x, N) : after rors {8,4,2,1} every lane holds its 16-row's sum.
#define RORADD(x, ctrl)                                                      \
  x += __int_as_float(__builtin_amdgcn_update_dpp(                           \
      0, __float_as_int(x), (ctrl), 0xf, 0xf, true))

#define SW32(a, b)                                                           \
  __builtin_amdgcn_permlane32_swap(__float_as_uint(a), __float_as_uint(b),   \
                                   false, false)
#define SW16(a, b)                                                           \
  __builtin_amdgcn_permlane16_swap(__float_as_uint(a), __float_as_uint(b),   \
                                   false, false)
#define UF(u) __uint_as_float(u)
#define RL(x, L) __int_as_float(__builtin_amdgcn_readlane(__float_as_int(x), (L)))

// Four independent 4-value 64-lane sums, hand-braided stage-by-stage so each
// cross-lane op's latency/hazard slots are filled by the other three chains.
// Row-mapped outputs (row g holds value sig(g), sig = [0,2,1,3]); all lanes valid.
__device__ __forceinline__ void allred4x4(
    float a0, float a1, float a2, float a3,
    float b0, float b1, float b2, float b3,
    float c0, float c1, float c2, float c3,
    float d0, float d1, float d2, float d3,
    float& ya, float& yb, float& yc, float& yd) {
  u32x2 sa1 = SW32(a0, a1), sb1 = SW32(b0, b1), sc1 = SW32(c0, c1),
        sd1 = SW32(d0, d1);
  u32x2 sa2 = SW32(a2, a3), sb2 = SW32(b2, b3), sc2 = SW32(c2, c3),
        sd2 = SW32(d2, d3);
  float za01 = UF(sa1.x) + UF(sa1.y), zb01 = UF(sb1.x) + UF(sb1.y),
        zc01 = UF(sc1.x) + UF(sc1.y), zd01 = UF(sd1.x) + UF(sd1.y);
  float za23 = UF(sa2.x) + UF(sa2.y), zb23 = UF(sb2.x) + UF(sb2.y),
        zc23 = UF(sc2.x) + UF(sc2.y), zd23 = UF(sd2.x) + UF(sd2.y);
  u32x2 ta = SW16(za01, za23), tb = SW16(zb01, zb23), tc = SW16(zc01, zc23),
        td = SW16(zd01, zd23);
  float ya_ = UF(ta.x) + UF(ta.y), yb_ = UF(tb.x) + UF(tb.y),
        yc_ = UF(tc.x) + UF(tc.y), yd_ = UF(td.x) + UF(td.y);
  RORADD(ya_, 0x128); RORADD(yb_, 0x128); RORADD(yc_, 0x128); RORADD(yd_, 0x128);
  RORADD(ya_, 0x124); RORADD(yb_, 0x124); RORADD(yc_, 0x124); RORADD(yd_, 0x124);
  RORADD(ya_, 0x122); RORADD(yb_, 0x122); RORADD(yc_, 0x122); RORADD(yd_, 0x122);
  RORADD(ya_, 0x121); RORADD(yb_, 0x121); RORADD(yc_, 0x121); RORADD(yd_, 0x121);
  ya = ya_; yb = yb_; yc = yc_; yd = yd_;
}

// single 4-value reduction (kk pair etc.), same mapping
__device__ __forceinline__ float allred4(float x0, float x1, float x2, float x3) {
  u32x2 s1 = SW32(x0, x1);
  u32x2 s2 = SW32(x2, x3);
  float z01 = UF(s1.x) + UF(s1.y);
  float z23 = UF(s2.x) + UF(s2.y);
  u32x2 s3 = SW16(z01, z23);
  float y = UF(s3.x) + UF(s3.y);
  RORADD(y, 0x128); RORADD(y, 0x124); RORADD(y, 0x122); RORADD(y, 0x121);
  return y;
}

// Two TTT chains (batches 2*blockIdx.x, +1) per 64-lane wave: independent
// dependency graphs braided in one instruction stream hide cross-lane latency.
__global__ __launch_bounds__(64) void ttt_kernel(
    const float* __restrict__ h, const float* __restrict__ W1,
    const float* __restrict__ b1, const float* __restrict__ W2,
    const float* __restrict__ b2, float* __restrict__ out) {
  const int bp = blockIdx.x * 2;
  const int lane = threadIdx.x;  // 0..63
  const int d0 = lane * 2;       // lane owns hidden dims d0, d0+1
  const float* __restrict__ hbP = h + (size_t)bp * (LSEQ * HIDDIM);
  const float* __restrict__ hbQ = hbP + (size_t)LSEQ * HIDDIM;
  const int g = lane >> 4;
  const int sig = ((g & 1) << 1) | (g >> 1);  // row g holds inner unit sig(g)

  // ---- weight state in registers (both chains start identical) ----
  float2 w1vP[8], w1vQ[8], w2vP[8], w2vQ[8];
#pragma unroll
  for (int i = 0; i < 8; ++i) {
    float2 t = *reinterpret_cast<const float2*>(W1 + i * HIDDIM + d0);
    w1vP[i] = t;
    w1vQ[i] = t;
    float2 u;
    u.x = W2[(size_t)d0 * 8 + i];
    u.y = W2[(size_t)(d0 + 1) * 8 + i];
    w2vP[i] = u;
    w2vQ[i] = u;
  }
  float2 b2c = *reinterpret_cast<const float2*>(b2 + d0);
  float2 b2vP = b2c, b2vQ = b2c;
  const float b1i0 = b1[sig], b1i1 = b1[4 + sig];
  float b1AP = b1i0, b1BP = b1i1, b1AQ = b1i0, b1BQ = b1i1;
  const float cneg = -(LRC * 2.0f / (float)HIDDIM);

  // ---- 3-slot k/v rotation per chain, prefetch distance ~2.5 steps ----
  const float* pfP = hbP + d0;
  const float* pfQ = hbQ + d0;
  float2 kAP = *(const float2*)(pfP + 0 * HIDDIM);
  float2 vAP = *(const float2*)(pfP + 1 * HIDDIM);
  float2 kBP = *(const float2*)(pfP + 2 * HIDDIM);
  float2 vBP = *(const float2*)(pfP + 3 * HIDDIM);
  float2 kCP = *(const float2*)(pfP + 4 * HIDDIM);
  float2 vCP = *(const float2*)(pfP + 5 * HIDDIM);
  float2 kAQ = *(const float2*)(pfQ + 0 * HIDDIM);
  float2 vAQ = *(const float2*)(pfQ + 1 * HIDDIM);
  float2 kBQ = *(const float2*)(pfQ + 2 * HIDDIM);
  float2 vBQ = *(const float2*)(pfQ + 3 * HIDDIM);
  float2 kCQ = *(const float2*)(pfQ + 4 * HIDDIM);
  float2 vCQ = *(const float2*)(pfQ + 5 * HIDDIM);
  pfP += 6 * HIDDIM;
  pfQ += 6 * HIDDIM;

  // ---- a(0) = W1 k(0) + b1, row-mapped, both chains ----
  float aAP, aBP, aAQ, aBQ;
  {
    float pP[8], pQ[8];
#pragma unroll
    for (int i = 0; i < 8; ++i) {
      pP[i] = fmaf(w1vP[i].x, kAP.x, w1vP[i].y * kAP.y);
      pQ[i] = fmaf(w1vQ[i].x, kAQ.x, w1vQ[i].y * kAQ.y);
    }
    float t0, t1, t2, t3;
    allred4x4(pP[0], pP[1], pP[2], pP[3], pP[4], pP[5], pP[6], pP[7],
              pQ[0], pQ[1], pQ[2], pQ[3], pQ[4], pQ[5], pQ[6], pQ[7],
              t0, t1, t2, t3);
    aAP = t0 + b1AP;
    aBP = t1 + b1BP;
    aAQ = t2 + b1AQ;
    aBQ = t3 + b1BQ;
  }

  // One SGD step s for BOTH chains. Rank-1 factorization keeps the serial
  // chain short: a(s+1) = red(W1(s)k(s+1)) + da(s)*(red(k(s)·k(s+1))+1) + b1(s)
  auto STEP2 = [&](float2 kP, float2 vP, float2 knP,
                   float2 kQ, float2 vQ, float2 knQ) {
    float rAP = fmaxf(aAP, 0.0f), rBP = fmaxf(aBP, 0.0f);
    float rAQ = fmaxf(aAQ, 0.0f), rBQ = fmaxf(aBQ, 0.0f);
    // broadcast r_i to SGPRs (value i lives at lane 16*sig(i))
    float rP[8] = {RL(rAP, 0), RL(rAP, 32), RL(rAP, 16), RL(rAP, 48),
                   RL(rBP, 0), RL(rBP, 32), RL(rBP, 16), RL(rBP, 48)};
    float rQ[8] = {RL(rAQ, 0), RL(rAQ, 32), RL(rAQ, 16), RL(rAQ, 48),
                   RL(rBQ, 0), RL(rBQ, 32), RL(rBQ, 16), RL(rBQ, 48)};
    // pred = W2 r + b2 (two partial accumulators per chain)
    float2 p0P, p1P, p0Q, p1Q;
    p0P.x = fmaf(w2vP[0].x, rP[0], b2vP.x);
    p0P.y = fmaf(w2vP[0].y, rP[0], b2vP.y);
    p1P.x = w2vP[1].x * rP[1];
    p1P.y = w2vP[1].y * rP[1];
    p0Q.x = fmaf(w2vQ[0].x, rQ[0], b2vQ.x);
    p0Q.y = fmaf(w2vQ[0].y, rQ[0], b2vQ.y);
    p1Q.x = w2vQ[1].x * rQ[1];
    p1Q.y = w2vQ[1].y * rQ[1];
#pragma unroll
    for (int i = 2; i < 8; i += 2) {
      p0P.x = fmaf(w2vP[i].x, rP[i], p0P.x);
      p0P.y = fmaf(w2vP[i].y, rP[i], p0P.y);
      p1P.x = fmaf(w2vP[i + 1].x, rP[i + 1], p1P.x);
      p1P.y = fmaf(w2vP[i + 1].y, rP[i + 1], p1P.y);
      p0Q.x = fmaf(w2vQ[i].x, rQ[i], p0Q.x);
      p0Q.y = fmaf(w2vQ[i].y, rQ[i], p0Q.y);
      p1Q.x = fmaf(w2vQ[i + 1].x, rQ[i + 1], p1Q.x);
      p1Q.y = fmaf(w2vQ[i + 1].y, rQ[i + 1], p1Q.y);
    }
    float2 glP, glQ;
    glP.x = (p0P.x + p1P.x - vP.x) * cneg;
    glP.y = (p0P.y + p1P.y - vP.y) * cneg;
    glQ.x = (p0Q.x + p1Q.x - vQ.x) * cneg;
    glQ.y = (p0Q.y + p1Q.y - vQ.y) * cneg;
    // dp partials from OLD w2
    float dpP[8], dpQ[8];
#pragma unroll
    for (int i = 0; i < 8; ++i) {
      dpP[i] = fmaf(w2vP[i].x, glP.x, w2vP[i].y * glP.y);
      dpQ[i] = fmaf(w2vQ[i].x, glQ.x, w2vQ[i].y * glQ.y);
    }
    float zAP, zBP, zAQ, zBQ;
    allred4x4(dpP[0], dpP[1], dpP[2], dpP[3], dpP[4], dpP[5], dpP[6], dpP[7],
              dpQ[0], dpQ[1], dpQ[2], dpQ[3], dpQ[4], dpQ[5], dpQ[6], dpQ[7],
              zAP, zBP, zAQ, zBQ);
    float daAP = (aAP > 0.0f) ? zAP : 0.0f;  // == -lr * da_ref, row-mapped
    float daBP = (aBP > 0.0f) ? zBP : 0.0f;
    float daAQ = (aAQ > 0.0f) ? zAQ : 0.0f;
    float daBQ = (aBQ > 0.0f) ? zBQ : 0.0f;
    // next-step a ingredients with OLD w1: tp = red(W1 k(s+1)), kk
    float tpP[8], tpQ[8];
#pragma unroll
    for (int i = 0; i < 8; ++i) {
      tpP[i] = fmaf(w1vP[i].x, knP.x, w1vP[i].y * knP.y);
      tpQ[i] = fmaf(w1vQ[i].x, knQ.x, w1vQ[i].y * knQ.y);
    }
    float kkpP = fmaf(kP.x, knP.x, kP.y * knP.y);
    float kkpQ = fmaf(kQ.x, knQ.x, kQ.y * knQ.y);
    float tAP, tBP, tAQ, tBQ;
    allred4x4(tpP[0], tpP[1], tpP[2], tpP[3], tpP[4], tpP[5], tpP[6], tpP[7],
              tpQ[0], tpQ[1], tpQ[2], tpQ[3], tpQ[4], tpQ[5], tpQ[6], tpQ[7],
              tAP, tBP, tAQ, tBQ);
    float ykk = allred4(kkpP, kkpQ, kkpP, kkpQ);  // x0 -> lane0, x1 -> lane32
    float kk1P = RL(ykk, 0) + 1.0f;
    float kk1Q = RL(ykk, 32) + 1.0f;
    // w2 / b2 updates (SGPR r_i)
#pragma unroll
    for (int i = 0; i < 8; ++i) {
      w2vP[i].x = fmaf(glP.x, rP[i], w2vP[i].x);
      w2vP[i].y = fmaf(glP.y, rP[i], w2vP[i].y);
      w2vQ[i].x = fmaf(glQ.x, rQ[i], w2vQ[i].x);
      w2vQ[i].y = fmaf(glQ.y, rQ[i], w2vQ[i].y);
    }
    b2vP.x += glP.x;
    b2vP.y += glP.y;
    b2vQ.x += glQ.x;
    b2vQ.y += glQ.y;
    // W1 updates: broadcast da_i to SGPRs, rank-1 add
    float eP[8] = {RL(daAP, 0), RL(daAP, 32), RL(daAP, 16), RL(daAP, 48),
                   RL(daBP, 0), RL(daBP, 32), RL(daBP, 16), RL(daBP, 48)};
    float eQ[8] = {RL(daAQ, 0), RL(daAQ, 32), RL(daAQ, 16), RL(daAQ, 48),
                   RL(daBQ, 0), RL(daBQ, 32), RL(daBQ, 16), RL(daBQ, 48)};
#pragma unroll
    for (int i = 0; i < 8; ++i) {
      w1vP[i].x = fmaf(eP[i], kP.x, w1vP[i].x);
      w1vP[i].y = fmaf(eP[i], kP.y, w1vP[i].y);
      w1vQ[i].x = fmaf(eQ[i], kQ.x, w1vQ[i].x);
      w1vQ[i].y = fmaf(eQ[i], kQ.y, w1vQ[i].y);
    }
    // a(s+1), b1 update (row-mapped; uses OLD b1)
    aAP = fmaf(daAP, kk1P, tAP + b1AP);
    aBP = fmaf(daBP, kk1P, tBP + b1BP);
    aAQ = fmaf(daAQ, kk1Q, tAQ + b1AQ);
    aBQ = fmaf(daBQ, kk1Q, tBQ + b1BQ);
    b1AP += daAP;
    b1BP += daBP;
    b1AQ += daAQ;
    b1BQ += daBQ;
  };

  // steps 0..2042: 681 iterations x 3 (3-slot rotation)
  for (int it = 0; it < 681; ++it) {
    {
      float2 kP = kAP, vP = vAP, knP = kBP;
      float2 kQ = kAQ, vQ = vAQ, knQ = kBQ;
      kAP = *(const float2*)(pfP + 0 * HIDDIM);
      vAP = *(const float2*)(pfP + 1 * HIDDIM);
      kAQ = *(const float2*)(pfQ + 0 * HIDDIM);
      vAQ = *(const float2*)(pfQ + 1 * HIDDIM);
      STEP2(kP, vP, knP, kQ, vQ, knQ);  // s = 3it
    }
    {
      float2 kP = kBP, vP = vBP, knP = kCP;
      float2 kQ = kBQ, vQ = vBQ, knQ = kCQ;
      kBP = *(const float2*)(pfP + 2 * HIDDIM);
      vBP = *(const float2*)(pfP + 3 * HIDDIM);
      kBQ = *(const float2*)(pfQ + 2 * HIDDIM);
      vBQ = *(const float2*)(pfQ + 3 * HIDDIM);
      STEP2(kP, vP, knP, kQ, vQ, knQ);  // s = 3it+1
    }
    {
      float2 kP = kCP, vP = vCP, knP = kAP;  // kn = freshly loaded k(3it+3)
      float2 kQ = kCQ, vQ = vCQ, knQ = kAQ;
      kCP = *(const float2*)(pfP + 4 * HIDDIM);
      vCP = *(const float2*)(pfP + 5 * HIDDIM);
      kCQ = *(const float2*)(pfQ + 4 * HIDDIM);
      vCQ = *(const float2*)(pfQ + 5 * HIDDIM);
      STEP2(kP, vP, knP, kQ, vQ, knQ);  // s = 3it+2
    }
    pfP += 6 * HIDDIM;
    pfQ += 6 * HIDDIM;
  }

  // tail: pf at row 4092. steps 2043..2046, then final predict with row 4095.
  float2 kDP = *(const float2*)(pfP + 0 * HIDDIM);
  float2 vDP = *(const float2*)(pfP + 1 * HIDDIM);
  float2 kEP = *(const float2*)(pfP + 2 * HIDDIM);
  float2 xvP = *(const float2*)(pfP + 3 * HIDDIM);
  float2 kDQ = *(const float2*)(pfQ + 0 * HIDDIM);
  float2 vDQ = *(const float2*)(pfQ + 1 * HIDDIM);
  float2 kEQ = *(const float2*)(pfQ + 2 * HIDDIM);
  float2 xvQ = *(const float2*)(pfQ + 3 * HIDDIM);
  STEP2(kAP, vAP, kBP, kAQ, vAQ, kBQ);  // 2043
  STEP2(kBP, vBP, kCP, kBQ, vBQ, kCQ);  // 2044
  STEP2(kCP, vCP, kDP, kCQ, vCQ, kDQ);  // 2045
  STEP2(kDP, vDP, kEP, kDQ, vDQ, kEQ);  // 2046 (kn only feeds a discarded a)

  // ---- final prediction with x = h[b, L-1], both chains ----
  {
    float pP[8], pQ[8];
#pragma unroll
    for (int i = 0; i < 8; ++i) {
      pP[i] = fmaf(w1vP[i].x, xvP.x, w1vP[i].y * xvP.y);
      pQ[i] = fmaf(w1vQ[i].x, xvQ.x, w1vQ[i].y * xvQ.y);
    }
    float fAP, fBP, fAQ, fBQ;
    allred4x4(pP[0], pP[1], pP[2], pP[3], pP[4], pP[5], pP[6], pP[7],
              pQ[0], pQ[1], pQ[2], pQ[3], pQ[4], pQ[5], pQ[6], pQ[7],
              fAP, fBP, fAQ, fBQ);
    float rAPf = fmaxf(fAP + b1AP, 0.0f), rBPf = fmaxf(fBP + b1BP, 0.0f);
    float rAQf = fmaxf(fAQ + b1AQ, 0.0f), rBQf = fmaxf(fBQ + b1BQ, 0.0f);
    float rP[8] = {RL(rAPf, 0), RL(rAPf, 32), RL(rAPf, 16), RL(rAPf, 48),
                   RL(rBPf, 0), RL(rBPf, 32), RL(rBPf, 16), RL(rBPf, 48)};
    float rQ[8] = {RL(rAQf, 0), RL(rAQf, 32), RL(rAQf, 16), RL(rAQf, 48),
                   RL(rBQf, 0), RL(rBQf, 32), RL(rBQf, 16), RL(rBQf, 48)};
    float2 oP = b2vP, oQ = b2vQ;
#pragma unroll
    for (int i = 0; i < 8; ++i) {
      oP.x = fmaf(w2vP[i].x, rP[i], oP.x);
      oP.y = fmaf(w2vP[i].y, rP[i], oP.y);
      oQ.x = fmaf(w2vQ[i].x, rQ[i], oQ.x);
      oQ.y = fmaf(w2vQ[i].y, rQ[i], oQ.y);
    }
    *reinterpret_cast<float2*>(out + (size_t)bp * HIDDIM + d0) = oP;
    *reinterpret_cast<float2*>(out + (size_t)(bp + 1) * HIDDIM + d0) = oQ;
  }
}

extern "C" void kernel_launch(void* const* d_in, const int* in_sizes, int n_in,
                              void* d_out, int out_size, void* d_ws, size_t ws_size,
                              hipStream_t stream) {
  const float* h  = (const float*)d_in[0];
  const float* W1 = (const float*)d_in[1];
  const float* b1 = (const float*)d_in[2];
  const float* W2 = (const float*)d_in[3];
  const float* b2 = (const float*)d_in[4];
  float* out = (float*)d_out;
  ttt_kernel<<<128, 64, 0, stream>>>(h, W1, b1, W2, b2, out);
}

// Round 10
// 649.964 us; speedup vs baseline: 1.9601x; 1.9601x over previous
//
#include <hip/hip_runtime.h>

#define LRC 0.01f
#define LSEQ 4096
#define HIDDIM 128

typedef float f32x2 __attribute__((ext_vector_type(2)));
typedef unsigned int u32x2 __attribute__((ext_vector_type(2)));

#define RL(x, L) __int_as_float(__builtin_amdgcn_readlane(__float_as_int(x), (L)))
#define PKFMA(a, b, c) __builtin_elementwise_fma((a), (b), (c))

// ---- intrinsic reduction (compiler-handled hazards) for init/final ----
#define RORADD(x, ctrl)                                                      \
  x += __int_as_float(__builtin_amdgcn_update_dpp(                           \
      0, __float_as_int(x), (ctrl), 0xf, 0xf, true))

// 4 concurrent 64-lane sums, ALL-LANES result, row-mapped:
// row g (lanes 16g..16g+15) holds sum(x_{sig(g)}), sig = [0,2,1,3].
__device__ __forceinline__ float allred4(float x0, float x1, float x2,
                                         float x3) {
  u32x2 s1 = __builtin_amdgcn_permlane32_swap(__float_as_uint(x0),
                                              __float_as_uint(x1), false, false);
  float z01 = __uint_as_float(s1.x) + __uint_as_float(s1.y);
  u32x2 s2 = __builtin_amdgcn_permlane32_swap(__float_as_uint(x2),
                                              __float_as_uint(x3), false, false);
  float z23 = __uint_as_float(s2.x) + __uint_as_float(s2.y);
  u32x2 s3 = __builtin_amdgcn_permlane16_swap(__float_as_uint(z01),
                                              __float_as_uint(z23), false, false);
  float y = __uint_as_float(s3.x) + __uint_as_float(s3.y);
  RORADD(y, 0x128);
  RORADD(y, 0x124);
  RORADD(y, 0x122);
  RORADD(y, 0x121);
  return y;
}

// ---- hot-loop reduction: 17 values in ONE hazard-safe asm block ----
// 5 chains braided stage-by-stage: every VALU-write -> lane-crossing-read
// pair has >=4 intervening instructions (HW needs 2); s_nop 1 covers the
// block boundary (compiler-written inputs read by the first swaps).
// Chains: d0..d3 -> zA, d4..d7 -> zB, t0..t3 -> tA, t4..t7 -> tB (all
// row-mapped, sig=[0,2,1,3], identical dataflow to allred4), c -> cU
// (all-lane uniform, identical dataflow to the validated allred1).
__device__ __forceinline__ void red17(
    float d0, float d1, float d2, float d3,
    float d4, float d5, float d6, float d7,
    float t0, float t1, float t2, float t3,
    float t4, float t5, float t6, float t7,
    float c,
    float& zA, float& zB, float& tA, float& tB, float& cU) {
  float tmp;
  asm volatile(
      "s_nop 1\n\t"
      "v_mov_b32 %17, %16\n\t"
      "v_permlane32_swap_b32 %0, %1\n\t"
      "v_permlane32_swap_b32 %2, %3\n\t"
      "v_permlane32_swap_b32 %4, %5\n\t"
      "v_permlane32_swap_b32 %6, %7\n\t"
      "v_permlane32_swap_b32 %8, %9\n\t"
      "v_permlane32_swap_b32 %10, %11\n\t"
      "v_permlane32_swap_b32 %12, %13\n\t"
      "v_permlane32_swap_b32 %14, %15\n\t"
      "v_permlane32_swap_b32 %16, %17\n\t"
      "v_add_f32 %0, %0, %1\n\t"
      "v_add_f32 %2, %2, %3\n\t"
      "v_add_f32 %4, %4, %5\n\t"
      "v_add_f32 %6, %6, %7\n\t"
      "v_add_f32 %8, %8, %9\n\t"
      "v_add_f32 %10, %10, %11\n\t"
      "v_add_f32 %12, %12, %13\n\t"
      "v_add_f32 %14, %14, %15\n\t"
      "v_add_f32 %16, %16, %17\n\t"
      "v_mov_b32 %17, %16\n\t"
      "v_permlane16_swap_b32 %0, %2\n\t"
      "v_permlane16_swap_b32 %4, %6\n\t"
      "v_permlane16_swap_b32 %8, %10\n\t"
      "v_permlane16_swap_b32 %12, %14\n\t"
      "v_permlane16_swap_b32 %16, %17\n\t"
      "v_add_f32 %0, %0, %2\n\t"
      "v_add_f32 %4, %4, %6\n\t"
      "v_add_f32 %8, %8, %10\n\t"
      "v_add_f32 %12, %12, %14\n\t"
      "v_add_f32 %16, %16, %17\n\t"
      "v_add_f32 %0, %0, %0 row_ror:8 row_mask:0xf bank_mask:0xf\n\t"
      "v_add_f32 %4, %4, %4 row_ror:8 row_mask:0xf bank_mask:0xf\n\t"
      "v_add_f32 %8, %8, %8 row_ror:8 row_mask:0xf bank_mask:0xf\n\t"
      "v_add_f32 %12, %12, %12 row_ror:8 row_mask:0xf bank_mask:0xf\n\t"
      "v_add_f32 %16, %16, %16 row_ror:8 row_mask:0xf bank_mask:0xf\n\t"
      "v_add_f32 %0, %0, %0 row_ror:4 row_mask:0xf bank_mask:0xf\n\t"
      "v_add_f32 %4, %4, %4 row_ror:4 row_mask:0xf bank_mask:0xf\n\t"
      "v_add_f32 %8, %8, %8 row_ror:4 row_mask:0xf bank_mask:0xf\n\t"
      "v_add_f32 %12, %12, %12 row_ror:4 row_mask:0xf bank_mask:0xf\n\t"
      "v_add_f32 %16, %16, %16 row_ror:4 row_mask:0xf bank_mask:0xf\n\t"
      "v_add_f32 %0, %0, %0 row_ror:2 row_mask:0xf bank_mask:0xf\n\t"
      "v_add_f32 %4, %4, %4 row_ror:2 row_mask:0xf bank_mask:0xf\n\t"
      "v_add_f32 %8, %8, %8 row_ror:2 row_mask:0xf bank_mask:0xf\n\t"
      "v_add_f32 %12, %12, %12 row_ror:2 row_mask:0xf bank_mask:0xf\n\t"
      "v_add_f32 %16, %16, %16 row_ror:2 row_mask:0xf bank_mask:0xf\n\t"
      "v_add_f32 %0, %0, %0 row_ror:1 row_mask:0xf bank_mask:0xf\n\t"
      "v_add_f32 %4, %4, %4 row_ror:1 row_mask:0xf bank_mask:0xf\n\t"
      "v_add_f32 %8, %8, %8 row_ror:1 row_mask:0xf bank_mask:0xf\n\t"
      "v_add_f32 %12, %12, %12 row_ror:1 row_mask:0xf bank_mask:0xf\n\t"
      "v_add_f32 %16, %16, %16 row_ror:1 row_mask:0xf bank_mask:0xf"
      : "+v"(d0), "+v"(d1), "+v"(d2), "+v"(d3),
        "+v"(d4), "+v"(d5), "+v"(d6), "+v"(d7),
        "+v"(t0), "+v"(t1), "+v"(t2), "+v"(t3),
        "+v"(t4), "+v"(t5), "+v"(t6), "+v"(t7),
        "+v"(c), "=&v"(tmp));
  zA = d0;
  zB = d4;
  tA = t0;
  tB = t4;
  cU = c;
}

__global__ __launch_bounds__(64) void ttt_kernel(
    const float* __restrict__ h, const float* __restrict__ W1,
    const float* __restrict__ b1, const float* __restrict__ W2,
    const float* __restrict__ b2, float* __restrict__ out) {
  const int b = blockIdx.x;
  const int lane = threadIdx.x;  // 0..63
  const int d0 = lane * 2;       // lane owns hidden dims d0, d0+1
  const float* __restrict__ hb = h + (size_t)b * (LSEQ * HIDDIM);
  const int g = lane >> 4;
  const int sig = ((g & 1) << 1) | (g >> 1);  // row g holds inner unit sig(g)

  // ---- weight state in registers ----
  f32x2 w1v[8];  // (W1[i][d0], W1[i][d0+1])
  f32x2 w2v[8];  // (W2[d0][i], W2[d0+1][i])
#pragma unroll
  for (int i = 0; i < 8; ++i) {
    w1v[i] = *reinterpret_cast<const f32x2*>(W1 + i * HIDDIM + d0);
    w2v[i].x = W2[(size_t)d0 * 8 + i];
    w2v[i].y = W2[(size_t)(d0 + 1) * 8 + i];
  }
  f32x2 b2v = *reinterpret_cast<const f32x2*>(b2 + d0);
  float b1A = b1[sig];      // row-mapped b1 state (i = sig(g))
  float b1B = b1[4 + sig];  // (i = 4 + sig(g))

  const float cneg = -(LRC * 2.0f / (float)HIDDIM);
  const f32x2 cnegv = {cneg, cneg};

  // ---- 3-slot k/v rotation, prefetch distance ~2.5 steps ----
  const float* pf = hb + d0;
  f32x2 kA = *reinterpret_cast<const f32x2*>(pf + 0 * HIDDIM);
  f32x2 vA = *reinterpret_cast<const f32x2*>(pf + 1 * HIDDIM);
  f32x2 kB = *reinterpret_cast<const f32x2*>(pf + 2 * HIDDIM);
  f32x2 vB = *reinterpret_cast<const f32x2*>(pf + 3 * HIDDIM);
  f32x2 kC = *reinterpret_cast<const f32x2*>(pf + 4 * HIDDIM);
  f32x2 vC = *reinterpret_cast<const f32x2*>(pf + 5 * HIDDIM);
  pf += 6 * HIDDIM;

  // ---- a(0) = W1 k(0) + b1, row-mapped (intrinsic path, off hot loop) ----
  float aA, aB;
  {
    float pa[8];
#pragma unroll
    for (int i = 0; i < 8; ++i) pa[i] = fmaf(w1v[i].x, kA.x, w1v[i].y * kA.y);
    aA = allred4(pa[0], pa[1], pa[2], pa[3]) + b1A;
    aB = allred4(pa[4], pa[5], pa[6], pa[7]) + b1B;
  }

  // One SGD step s. In: a(s) row-mapped (aA,aB), k(s), v(s), k(s+1).
  // Rank-1 factorization:
  //   a(s+1) = red(W1(s) k(s+1)) + da(s)*(red(k(s)·k(s+1)) + 1) + b1(s)
  auto STEP = [&](f32x2 k, f32x2 v, f32x2 kn) {
    // tp/kk partials with OLD w1 (independent of this step's serial core)
    float tp[8];
#pragma unroll
    for (int i = 0; i < 8; ++i) tp[i] = fmaf(w1v[i].x, kn.x, w1v[i].y * kn.y);
    float kkp = fmaf(k.x, kn.x, k.y * kn.y);
    // relu + uniform broadcasts (value i lives at lane 16*sig(i))
    float rA = fmaxf(aA, 0.0f), rB = fmaxf(aB, 0.0f);
    float r0 = RL(rA, 0), r1 = RL(rA, 32), r2 = RL(rA, 16), r3 = RL(rA, 48);
    float r4 = RL(rB, 0), r5 = RL(rB, 32), r6 = RL(rB, 16), r7 = RL(rB, 48);
    f32x2 rr0 = {r0, r0}, rr1 = {r1, r1}, rr2 = {r2, r2}, rr3 = {r3, r3};
    f32x2 rr4 = {r4, r4}, rr5 = {r5, r5}, rr6 = {r6, r6}, rr7 = {r7, r7};
    // pred = W2 r + b2 (packed, two partial accumulators)
    f32x2 p0 = PKFMA(w2v[0], rr0, b2v);
    f32x2 p1 = w2v[1] * rr1;
    p0 = PKFMA(w2v[2], rr2, p0);
    p1 = PKFMA(w2v[3], rr3, p1);
    p0 = PKFMA(w2v[4], rr4, p0);
    p1 = PKFMA(w2v[5], rr5, p1);
    p0 = PKFMA(w2v[6], rr6, p0);
    p1 = PKFMA(w2v[7], rr7, p1);
    f32x2 gl = ((p0 + p1) - v) * cnegv;
    // dp partials from OLD w2
    float dp[8];
#pragma unroll
    for (int i = 0; i < 8; ++i) dp[i] = fmaf(w2v[i].x, gl.x, w2v[i].y * gl.y);
    // merged 17-value reduction (hazard-safe asm)
    float zA, zB, tA, tB, kkU;
    red17(dp[0], dp[1], dp[2], dp[3], dp[4], dp[5], dp[6], dp[7],
          tp[0], tp[1], tp[2], tp[3], tp[4], tp[5], tp[6], tp[7], kkp,
          zA, zB, tA, tB, kkU);
    // mask by a>0 (row-mapped, aligned layouts)
    float daA = (aA > 0.0f) ? zA : 0.0f;  // == -lr * da_ref
    float daB = (aB > 0.0f) ? zB : 0.0f;
    // w2 / b2 update (packed)
    w2v[0] = PKFMA(gl, rr0, w2v[0]);
    w2v[1] = PKFMA(gl, rr1, w2v[1]);
    w2v[2] = PKFMA(gl, rr2, w2v[2]);
    w2v[3] = PKFMA(gl, rr3, w2v[3]);
    w2v[4] = PKFMA(gl, rr4, w2v[4]);
    w2v[5] = PKFMA(gl, rr5, w2v[5]);
    w2v[6] = PKFMA(gl, rr6, w2v[6]);
    w2v[7] = PKFMA(gl, rr7, w2v[7]);
    b2v += gl;
    // W1 update: da_i to SGPR, packed rank-1 add
    float e0 = RL(daA, 0), e1 = RL(daA, 32), e2 = RL(daA, 16), e3 = RL(daA, 48);
    float e4 = RL(daB, 0), e5 = RL(daB, 32), e6 = RL(daB, 16), e7 = RL(daB, 48);
    f32x2 ee0 = {e0, e0}, ee1 = {e1, e1}, ee2 = {e2, e2}, ee3 = {e3, e3};
    f32x2 ee4 = {e4, e4}, ee5 = {e5, e5}, ee6 = {e6, e6}, ee7 = {e7, e7};
    w1v[0] = PKFMA(ee0, k, w1v[0]);
    w1v[1] = PKFMA(ee1, k, w1v[1]);
    w1v[2] = PKFMA(ee2, k, w1v[2]);
    w1v[3] = PKFMA(ee3, k, w1v[3]);
    w1v[4] = PKFMA(ee4, k, w1v[4]);
    w1v[5] = PKFMA(ee5, k, w1v[5]);
    w1v[6] = PKFMA(ee6, k, w1v[6]);
    w1v[7] = PKFMA(ee7, k, w1v[7]);
    // a(s+1), b1 update (row-mapped; uses OLD b1)
    float kkp1 = kkU + 1.0f;
    aA = fmaf(daA, kkp1, tA + b1A);
    aB = fmaf(daB, kkp1, tB + b1B);
    b1A += daA;
    b1B += daB;
  };

  // steps 0..2042: 681 iterations x 3 (3-slot rotation)
  for (int it = 0; it < 681; ++it) {
    {
      f32x2 k = kA, v = vA, kn = kB;
      kA = *reinterpret_cast<const f32x2*>(pf + 0 * HIDDIM);
      vA = *reinterpret_cast<const f32x2*>(pf + 1 * HIDDIM);
      STEP(k, v, kn);  // s = 3it
    }
    {
      f32x2 k = kB, v = vB, kn = kC;
      kB = *reinterpret_cast<const f32x2*>(pf + 2 * HIDDIM);
      vB = *reinterpret_cast<const f32x2*>(pf + 3 * HIDDIM);
      STEP(k, v, kn);  // s = 3it+1
    }
    {
      f32x2 k = kC, v = vC, kn = kA;  // kn = freshly loaded k(3it+3)
      kC = *reinterpret_cast<const f32x2*>(pf + 4 * HIDDIM);
      vC = *reinterpret_cast<const f32x2*>(pf + 5 * HIDDIM);
      STEP(k, v, kn);  // s = 3it+2
    }
    pf += 6 * HIDDIM;
  }

  // tail: pf at row 4092. steps 2043..2046, then final predict with row 4095.
  f32x2 kD = *reinterpret_cast<const f32x2*>(pf + 0 * HIDDIM);  // row 4092
  f32x2 vD = *reinterpret_cast<const f32x2*>(pf + 1 * HIDDIM);  // row 4093
  f32x2 kE = *reinterpret_cast<const f32x2*>(pf + 2 * HIDDIM);  // row 4094
  f32x2 xv = *reinterpret_cast<const f32x2*>(pf + 3 * HIDDIM);  // row 4095
  STEP(kA, vA, kB);  // 2043
  STEP(kB, vB, kC);  // 2044
  STEP(kC, vC, kD);  // 2045
  STEP(kD, vD, kE);  // 2046 (kn only feeds a discarded a)

  // ---- final prediction with x = h[b, L-1] (intrinsic path) ----
  {
    float pa[8];
#pragma unroll
    for (int i = 0; i < 8; ++i) pa[i] = fmaf(w1v[i].x, xv.x, w1v[i].y * xv.y);
    float fA = fmaxf(allred4(pa[0], pa[1], pa[2], pa[3]) + b1A, 0.0f);
    float fB = fmaxf(allred4(pa[4], pa[5], pa[6], pa[7]) + b1B, 0.0f);
    float r0 = RL(fA, 0), r1 = RL(fA, 32), r2 = RL(fA, 16), r3 = RL(fA, 48);
    float r4 = RL(fB, 0), r5 = RL(fB, 32), r6 = RL(fB, 16), r7 = RL(fB, 48);
    f32x2 o = b2v;
    o.x = fmaf(w2v[0].x, r0, o.x); o.y = fmaf(w2v[0].y, r0, o.y);
    o.x = fmaf(w2v[1].x, r1, o.x); o.y = fmaf(w2v[1].y, r1, o.y);
    o.x = fmaf(w2v[2].x, r2, o.x); o.y = fmaf(w2v[2].y, r2, o.y);
    o.x = fmaf(w2v[3].x, r3, o.x); o.y = fmaf(w2v[3].y, r3, o.y);
    o.x = fmaf(w2v[4].x, r4, o.x); o.y = fmaf(w2v[4].y, r4, o.y);
    o.x = fmaf(w2v[5].x, r5, o.x); o.y = fmaf(w2v[5].y, r5, o.y);
    o.x = fmaf(w2v[6].x, r6, o.x); o.y = fmaf(w2v[6].y, r6, o.y);
    o.x = fmaf(w2v[7].x, r7, o.x); o.y = fmaf(w2v[7].y, r7, o.y);
    *reinterpret_cast<f32x2*>(out + (size_t)b * HIDDIM + d0) = o;
  }
}

extern "C" void kernel_launch(void* const* d_in, const int* in_sizes, int n_in,
                              void* d_out, int out_size, void* d_ws, size_t ws_size,
                              hipStream_t stream) {
  const float* h  = (const float*)d_in[0];
  const float* W1 = (const float*)d_in[1];
  const float* b1 = (const float*)d_in[2];
  const float* W2 = (const float*)d_in[3];
  const float* b2 = (const float*)d_in[4];
  float* out = (float*)d_out;
  ttt_kernel<<<256, 64, 0, stream>>>(h, W1, b1, W2, b2, out);
}